// Round 1
// baseline (2180.026 us; speedup 1.0000x reference)
//
#include <hip/hip_runtime.h>
#include <math.h>

#define CC   16
#define HH   256
#define WW   256
#define HIDN 128
#define PDIM 144     // C*K*K
#define WO   128
#define TILE 64      // locations per block
#define HT_PITCH 68  // pitch for transposed h tile (mult of 4, not mult of 64)

// ---------------------------------------------------------------------------
// Kernel A: unfold (reflect pad) -> MLP (144->128 relu ->144) -> fold (atomic)
// folded accumulates directly into the cropped output buffer (B,16,256,256);
// padded-border positions (pad coords 0 / 257) are never needed and skipped.
// ---------------------------------------------------------------------------
__global__ __launch_bounds__(256) void mlp_fold_kernel(
    const float* __restrict__ x,  const float* __restrict__ W1,
    const float* __restrict__ b1, const float* __restrict__ W2,
    const float* __restrict__ b2, float* __restrict__ folded)
{
    __shared__ __align__(16) float pT[PDIM * TILE];      // [p][loc]
    __shared__ __align__(16) float hT[HIDN * HT_PITCH];  // [h][loc], padded pitch

    const int tid       = threadIdx.x;
    const int tile      = blockIdx.x & 255;   // 256 tiles / batch (16384/64)
    const int b         = blockIdx.x >> 8;
    const int tile_base = tile * TILE;

    // ---- stage patch tile: pT[p][lo] = x_pad[c][2a+i][2b+j] (reflect pad 1)
    const float* xb = x + (size_t)b * CC * HH * WW;
    for (int idx = tid; idx < PDIM * TILE; idx += 256) {
        const int p   = idx >> 6;
        const int lo  = idx & 63;
        const int c   = p / 9;
        const int rem = p - c * 9;
        const int i   = rem / 3;
        const int j   = rem - i * 3;
        const int l   = tile_base + lo;
        const int a   = l >> 7;      // row in 128x128 grid of patches
        const int bb  = l & 127;
        int ym = 2 * a + i - 1;      // padded coord - 1 = original coord
        int xm = 2 * bb + j - 1;
        if (ym < 0) ym = 1;          // reflect (only -1 can occur; max is 255)
        if (xm < 0) xm = 1;
        pT[p * TILE + lo] = xb[(c * HH + ym) * WW + xm];
    }
    __syncthreads();

    // ---- GEMM1: h[loc][hid] = relu(sum_p pT[p][loc] * W1[p][hid] + b1[hid])
    // thread tile: 8 rows (locations) x 4 cols (hid)
    {
        const int cg    = tid & 31;   // 32 col groups of 4 -> 128 hid
        const int rg    = tid >> 5;   // 8 row groups of 8  -> 64 locs
        const int rbase = rg * 8;
        float acc[8][4];
        #pragma unroll
        for (int m = 0; m < 8; ++m)
            #pragma unroll
            for (int jj = 0; jj < 4; ++jj) acc[m][jj] = 0.f;

        for (int k = 0; k < PDIM; ++k) {
            const float4 w  = *reinterpret_cast<const float4*>(W1 + k * HIDN + cg * 4);
            const float4 pa = *reinterpret_cast<const float4*>(pT + k * TILE + rbase);
            const float4 pb = *reinterpret_cast<const float4*>(pT + k * TILE + rbase + 4);
            const float pv[8] = {pa.x, pa.y, pa.z, pa.w, pb.x, pb.y, pb.z, pb.w};
            const float wv[4] = {w.x, w.y, w.z, w.w};
            #pragma unroll
            for (int m = 0; m < 8; ++m)
                #pragma unroll
                for (int jj = 0; jj < 4; ++jj)
                    acc[m][jj] = fmaf(pv[m], wv[jj], acc[m][jj]);
        }

        #pragma unroll
        for (int jj = 0; jj < 4; ++jj) {
            const int   jcol = cg * 4 + jj;
            const float bj   = b1[jcol];
            #pragma unroll
            for (int m = 0; m < 8; ++m) {
                const float hval = acc[m][jj] + bj;
                hT[jcol * HT_PITCH + rbase + m] = hval > 0.f ? hval : 0.f;
            }
        }
    }
    __syncthreads();

    // ---- GEMM2: o[loc][col] = sum_h hT[h][loc] * W2[h][col] + b2[col]
    // thread tile: 4 rows (locations) x 9 cols = one channel's 9 (i,j) taps
    {
        const int cg2 = tid & 15;    // channel c (9 cols each)
        const int rg2 = tid >> 4;    // 16 row groups of 4
        const int rb2 = rg2 * 4;
        float acc2[4][9];
        #pragma unroll
        for (int m = 0; m < 4; ++m)
            #pragma unroll
            for (int jj = 0; jj < 9; ++jj) acc2[m][jj] = 0.f;

        const float* w2base = W2 + cg2 * 9;
        for (int h = 0; h < HIDN; ++h) {
            const float4 hv4 = *reinterpret_cast<const float4*>(hT + h * HT_PITCH + rb2);
            const float  hv[4] = {hv4.x, hv4.y, hv4.z, hv4.w};
            float wv[9];
            #pragma unroll
            for (int jj = 0; jj < 9; ++jj) wv[jj] = w2base[h * PDIM + jj];
            #pragma unroll
            for (int m = 0; m < 4; ++m)
                #pragma unroll
                for (int jj = 0; jj < 9; ++jj)
                    acc2[m][jj] = fmaf(hv[m], wv[jj], acc2[m][jj]);
        }

        float bv[9];
        #pragma unroll
        for (int jj = 0; jj < 9; ++jj) bv[jj] = b2[cg2 * 9 + jj];

        float* fb = folded + ((size_t)b * CC + cg2) * (HH * WW);
        #pragma unroll
        for (int m = 0; m < 4; ++m) {
            const int l  = tile_base + rb2 + m;
            const int a  = l >> 7;
            const int bb = l & 127;
            #pragma unroll
            for (int jj = 0; jj < 9; ++jj) {
                const int i    = jj / 3;        // constants after unroll
                const int j2   = jj - i * 3;
                const int ypad = 2 * a + i;     // 0..256
                const int xpad = 2 * bb + j2;   // 0..256
                if (ypad >= 1 && xpad >= 1) {
                    atomicAdd(fb + (ypad - 1) * WW + (xpad - 1),
                              acc2[m][jj] + bv[jj]);
                }
            }
        }
    }
}

// ---------------------------------------------------------------------------
// Kernel B: normalize by analytic fold counts, 16x16 channel mix, softmax
// over channels, modulate; in-place on the folded/output buffer.
// ---------------------------------------------------------------------------
__global__ __launch_bounds__(256) void norm_softmax_kernel(
    float* __restrict__ out, const float* __restrict__ Wc,
    const float* __restrict__ bc)
{
    const int xo = threadIdx.x;           // 0..255
    const int yo = blockIdx.x & 255;      // 0..255
    const int b  = blockIdx.x >> 8;       // 0..31

    const int yp = yo + 1;                // padded coords 1..256
    const int xp = xo + 1;
    const float cy  = ((yp & 1) || yp == 256) ? 1.f : 2.f;
    const float cx  = ((xp & 1) || xp == 256) ? 1.f : 2.f;
    const float inv = 1.f / (cy * cx + 1e-6f);

    const size_t base = ((size_t)b * CC) * (HH * WW) + (size_t)yo * WW + xo;

    float nrm[CC];
    #pragma unroll
    for (int c = 0; c < CC; ++c)
        nrm[c] = out[base + (size_t)c * (HH * WW)] * inv;

    float logits[CC];
    #pragma unroll
    for (int o = 0; o < CC; ++o) {
        float s = bc[o];
        #pragma unroll
        for (int c = 0; c < CC; ++c)
            s = fmaf(Wc[o * CC + c], nrm[c], s);
        logits[o] = s;
    }

    float mx = logits[0];
    #pragma unroll
    for (int o = 1; o < CC; ++o) mx = fmaxf(mx, logits[o]);
    float se = 0.f;
    #pragma unroll
    for (int o = 0; o < CC; ++o) { logits[o] = expf(logits[o] - mx); se += logits[o]; }
    const float isum = 1.f / se;

    #pragma unroll
    for (int c = 0; c < CC; ++c)
        out[base + (size_t)c * (HH * WW)] = nrm[c] * logits[c] * isum;
}

// ---------------------------------------------------------------------------
extern "C" void kernel_launch(void* const* d_in, const int* in_sizes, int n_in,
                              void* d_out, int out_size, void* d_ws, size_t ws_size,
                              hipStream_t stream)
{
    const float* x  = (const float*)d_in[0];
    const float* W1 = (const float*)d_in[1];
    const float* b1 = (const float*)d_in[2];
    const float* W2 = (const float*)d_in[3];
    const float* b2 = (const float*)d_in[4];
    const float* Wc = (const float*)d_in[5];
    const float* bc = (const float*)d_in[6];
    float* out = (float*)d_out;

    // fold accumulates into d_out -> must start from zero (harness poisons it)
    hipMemsetAsync(d_out, 0, (size_t)out_size * sizeof(float), stream);

    // 32 batches * 256 tiles (of 64 locations) each
    mlp_fold_kernel<<<dim3(32 * 256), dim3(256), 0, stream>>>(x, W1, b1, W2, b2, out);

    // 32 batches * 256 rows, one thread per pixel
    norm_softmax_kernel<<<dim3(32 * 256), dim3(256), 0, stream>>>(out, Wc, bc);
}

// Round 2
// 456.233 us; speedup vs baseline: 4.7783x; 4.7783x over previous
//
#include <hip/hip_runtime.h>
#include <math.h>

#define CC   16
#define HH   256
#define WW   256
#define HIDN 128
#define PDIM 144     // C*K*K
#define K1PAD 160    // GEMM1 K padded to multiple of 32
#define PITCH_P 168  // LDS pitch for patch tile (halfs): 336B, 16B-mult, 2-way banks
#define PITCH_H 136  // LDS pitch for h tile (halfs): 272B, 16B-mult, 2-way banks

typedef _Float16 half8 __attribute__((ext_vector_type(8)));
typedef float   f32x4 __attribute__((ext_vector_type(4)));

#define MFMA16(a, b, c) __builtin_amdgcn_mfma_f32_16x16x32_f16((a), (b), (c), 0, 0, 0)

// ws layout
#define O_BYTES   ((size_t)524288 * 144 * 2)          // 150,994,944
#define W1T_OFF   O_BYTES                              // [n=128][k=160] fp16
#define W1T_BYTES ((size_t)128 * K1PAD * 2)            // 40,960
#define W2T_OFF   (W1T_OFF + W1T_BYTES)                // [nn=144][k=128] fp16, col-permuted
#define W2T_BYTES ((size_t)144 * 128 * 2)              // 36,864
#define WS_NEEDED (W2T_OFF + W2T_BYTES)

// ---------------------------------------------------------------------------
// Prep: build fp16 transposed weights in d_ws (every launch; graph-safe).
// W1T[n][k] = W1[k][n], zero-padded k>=144.
// W2T[nn][k] = W2[k][norig], nn = tap*16 + c permutation of norig = c*9 + tap
//   -> o rows become [tap][c] so the gather reads 16 contiguous channels.
// ---------------------------------------------------------------------------
__global__ __launch_bounds__(256) void prep_kernel(
    const float* __restrict__ W1, const float* __restrict__ W2,
    _Float16* __restrict__ W1T, _Float16* __restrict__ W2T)
{
    const int idx = blockIdx.x * 256 + threadIdx.x;
    if (idx < 128 * K1PAD) {
        const int n = idx / K1PAD;
        const int k = idx - n * K1PAD;
        W1T[idx] = (k < PDIM) ? (_Float16)W1[k * HIDN + n] : (_Float16)0.f;
    }
    if (idx < 144 * 128) {
        const int nn = idx >> 7;          // 0..143
        const int k  = idx & 127;
        const int tap = nn >> 4;          // 0..8
        const int c   = nn & 15;
        const int norig = c * 9 + tap;
        W2T[nn * 128 + k] = (_Float16)W2[k * PDIM + norig];
    }
}

// ---------------------------------------------------------------------------
// Kernel A: unfold (reflect pad) -> fp16 MFMA MLP -> write o to d_ws.
// One block = one patch row a (128 patches) of one batch. No atomics.
// ---------------------------------------------------------------------------
__global__ __launch_bounds__(256) void mlp_kernel(
    const float* __restrict__ x,
    const _Float16* __restrict__ W1T, const float* __restrict__ b1,
    const _Float16* __restrict__ W2T, const float* __restrict__ b2,
    _Float16* __restrict__ og)
{
    __shared__ __align__(16) _Float16 pT[128 * PITCH_P];  // [patch][k=0..159]
    __shared__ __align__(16) _Float16 hT[128 * PITCH_H];  // [patch][k=0..127]

    const int tid   = threadIdx.x;
    const int a     = blockIdx.x & 127;   // patch row
    const int batch = blockIdx.x >> 7;

    // ---- stage patches: pT[bcol][p] = x_pad[c][2a+i][2bcol+j] (reflect pad 1)
    const float* xb = x + (size_t)batch * CC * HH * WW;
    for (int idx = tid; idx < 128 * PDIM; idx += 256) {
        const int p    = idx >> 7;        // 0..143
        const int bcol = idx & 127;
        const int c    = p / 9;
        const int rem  = p - c * 9;
        const int i    = rem / 3;
        const int j    = rem - i * 3;
        int ym = 2 * a + i - 1;           // -1..255 ; reflect only at -1
        int xm = 2 * bcol + j - 1;
        if (ym < 0) ym = 1;
        if (xm < 0) xm = 1;
        pT[bcol * PITCH_P + p] = (_Float16)xb[(c * HH + ym) * WW + xm];
    }
    // zero pad k = 144..159
    for (int idx = tid; idx < 128 * 16; idx += 256) {
        const int bcol = idx >> 4;
        pT[bcol * PITCH_P + PDIM + (idx & 15)] = (_Float16)0.f;
    }
    __syncthreads();

    const int wid  = tid >> 6;
    const int lane = tid & 63;
    const int l15  = lane & 15;
    const int quad = lane >> 4;

    // ---- GEMM1: h = relu(patches @ W1 + b1).  M=128, N=128, K=160.
    // wave owns ntiles {2w, 2w+1}; B fragments live in registers.
    {
        half8 bfr[2][5];
        float bias[2];
        #pragma unroll
        for (int n = 0; n < 2; ++n) {
            const int nt = 2 * wid + n;
            const _Float16* wrow = W1T + (nt * 16 + l15) * K1PAD + quad * 8;
            #pragma unroll
            for (int ks = 0; ks < 5; ++ks)
                bfr[n][ks] = *(const half8*)(wrow + ks * 32);
            bias[n] = b1[nt * 16 + l15];
        }
        for (int mt = 0; mt < 8; ++mt) {
            f32x4 acc0 = {0.f, 0.f, 0.f, 0.f};
            f32x4 acc1 = {0.f, 0.f, 0.f, 0.f};
            const _Float16* arow = pT + (mt * 16 + l15) * PITCH_P + quad * 8;
            #pragma unroll
            for (int ks = 0; ks < 5; ++ks) {
                const half8 af = *(const half8*)(arow + ks * 32);
                acc0 = MFMA16(af, bfr[0][ks], acc0);
                acc1 = MFMA16(af, bfr[1][ks], acc1);
            }
            #pragma unroll
            for (int r = 0; r < 4; ++r) {
                const int row = mt * 16 + quad * 4 + r;
                float h0 = acc0[r] + bias[0];
                float h1 = acc1[r] + bias[1];
                hT[row * PITCH_H + (2 * wid) * 16 + l15]     = (_Float16)(h0 > 0.f ? h0 : 0.f);
                hT[row * PITCH_H + (2 * wid + 1) * 16 + l15] = (_Float16)(h1 > 0.f ? h1 : 0.f);
            }
        }
    }
    __syncthreads();

    // ---- GEMM2: o = h @ W2perm + b2perm.  M=128, N=144, K=128.
    // o global layout: [patch][tap*16 + c] fp16 (pitch 144).
    const size_t patch_base = (size_t)batch * 16384 + (size_t)a * 128;
    for (int nt = wid; nt < 9; nt += 4) {
        half8 bfr2[4];
        const _Float16* w2row = W2T + (nt * 16 + l15) * 128 + quad * 8;
        #pragma unroll
        for (int ks = 0; ks < 4; ++ks)
            bfr2[ks] = *(const half8*)(w2row + ks * 32);
        // permuted column nn = nt*16 + l15 -> norig = l15*9 + nt
        const float bias2 = b2[l15 * 9 + nt];
        for (int mt = 0; mt < 8; ++mt) {
            f32x4 acc = {0.f, 0.f, 0.f, 0.f};
            const _Float16* arow = hT + (mt * 16 + l15) * PITCH_H + quad * 8;
            #pragma unroll
            for (int ks = 0; ks < 4; ++ks)
                acc = MFMA16(*(const half8*)(arow + ks * 32), bfr2[ks], acc);
            #pragma unroll
            for (int r = 0; r < 4; ++r) {
                const size_t prow = patch_base + mt * 16 + quad * 4 + r;
                og[prow * 144 + nt * 16 + l15] = (_Float16)(acc[r] + bias2);
            }
        }
    }
}

// ---------------------------------------------------------------------------
// Kernel B: gather-fold (no atomics) + analytic-count normalize + 16x16
// channel mix + softmax + modulate. One thread per output pixel.
// ---------------------------------------------------------------------------
__global__ __launch_bounds__(256) void gather_kernel(
    const _Float16* __restrict__ og, const float* __restrict__ Wc,
    const float* __restrict__ bc, float* __restrict__ out)
{
    __shared__ float sWc[256];
    __shared__ float sbc[16];
    const int tid = threadIdx.x;
    sWc[tid] = Wc[tid];
    if (tid < 16) sbc[tid] = bc[tid];
    __syncthreads();

    const int x     = tid;                 // 0..255
    const int y     = blockIdx.x & 255;
    const int batch = blockIdx.x >> 8;

    // contributing patch rows (a, i): ypad = y+1 = 2a + i
    int alist[2], ilist[2], na = 0;
    if ((y + 1) & 1) { alist[0] = y >> 1; ilist[0] = 1; na = 1; }
    else {
        if (y < 255) { alist[na] = (y + 1) >> 1; ilist[na] = 0; ++na; }
        alist[na] = (y - 1) >> 1; ilist[na] = 2; ++na;
    }
    int blist[2], jlist[2], nb = 0;
    if ((x + 1) & 1) { blist[0] = x >> 1; jlist[0] = 1; nb = 1; }
    else {
        if (x < 255) { blist[nb] = (x + 1) >> 1; jlist[nb] = 0; ++nb; }
        blist[nb] = (x - 1) >> 1; jlist[nb] = 2; ++nb;
    }

    float nrm[CC];
    #pragma unroll
    for (int c = 0; c < CC; ++c) nrm[c] = 0.f;

    const size_t pb = (size_t)batch * 16384;
    for (int u = 0; u < 2; ++u) {
        if (u >= na) break;
        for (int v = 0; v < 2; ++v) {
            if (v >= nb) break;
            const int tap = ilist[u] * 3 + jlist[v];
            const _Float16* orow = og + (pb + (size_t)alist[u] * 128 + blist[v]) * 144 + tap * 16;
            const half8 o0 = *(const half8*)(orow);
            const half8 o1 = *(const half8*)(orow + 8);
            #pragma unroll
            for (int e = 0; e < 8; ++e) { nrm[e] += (float)o0[e]; nrm[8 + e] += (float)o1[e]; }
        }
    }
    const float inv = 1.f / ((float)(na * nb) + 1e-6f);
    #pragma unroll
    for (int c = 0; c < CC; ++c) nrm[c] *= inv;

    float lg[CC];
    #pragma unroll
    for (int o = 0; o < CC; ++o) {
        float s = sbc[o];
        #pragma unroll
        for (int c = 0; c < CC; ++c) s = fmaf(sWc[o * CC + c], nrm[c], s);
        lg[o] = s;
    }
    float mx = lg[0];
    #pragma unroll
    for (int o = 1; o < CC; ++o) mx = fmaxf(mx, lg[o]);
    float se = 0.f;
    #pragma unroll
    for (int o = 0; o < CC; ++o) { lg[o] = expf(lg[o] - mx); se += lg[o]; }
    const float isum = 1.f / se;

    const size_t obase = ((size_t)batch * CC) * (HH * WW) + (size_t)y * WW + x;
    #pragma unroll
    for (int c = 0; c < CC; ++c)
        out[obase + (size_t)c * (HH * WW)] = nrm[c] * lg[c] * isum;
}

// ===========================================================================
// FALLBACK (round-1 path) — used only if ws_size is too small.
// ===========================================================================
#define HT_PITCH 68
__global__ __launch_bounds__(256) void mlp_fold_kernel_fb(
    const float* __restrict__ x,  const float* __restrict__ W1,
    const float* __restrict__ b1, const float* __restrict__ W2,
    const float* __restrict__ b2, float* __restrict__ folded)
{
    __shared__ __align__(16) float pT[PDIM * 64];
    __shared__ __align__(16) float hT[HIDN * HT_PITCH];
    const int tid = threadIdx.x;
    const int tile = blockIdx.x & 255;
    const int b = blockIdx.x >> 8;
    const int tile_base = tile * 64;
    const float* xb = x + (size_t)b * CC * HH * WW;
    for (int idx = tid; idx < PDIM * 64; idx += 256) {
        const int p = idx >> 6, lo = idx & 63;
        const int c = p / 9, rem = p - c * 9, i = rem / 3, j = rem - i * 3;
        const int l = tile_base + lo, a = l >> 7, bb = l & 127;
        int ym = 2 * a + i - 1, xm = 2 * bb + j - 1;
        if (ym < 0) ym = 1;
        if (xm < 0) xm = 1;
        pT[p * 64 + lo] = xb[(c * HH + ym) * WW + xm];
    }
    __syncthreads();
    {
        const int cg = tid & 31, rg = tid >> 5, rbase = rg * 8;
        float acc[8][4];
        #pragma unroll
        for (int m = 0; m < 8; ++m)
            #pragma unroll
            for (int jj = 0; jj < 4; ++jj) acc[m][jj] = 0.f;
        for (int k = 0; k < PDIM; ++k) {
            const float4 w = *reinterpret_cast<const float4*>(W1 + k * HIDN + cg * 4);
            const float4 pa = *reinterpret_cast<const float4*>(pT + k * 64 + rbase);
            const float4 pb2 = *reinterpret_cast<const float4*>(pT + k * 64 + rbase + 4);
            const float pv[8] = {pa.x, pa.y, pa.z, pa.w, pb2.x, pb2.y, pb2.z, pb2.w};
            const float wv[4] = {w.x, w.y, w.z, w.w};
            #pragma unroll
            for (int m = 0; m < 8; ++m)
                #pragma unroll
                for (int jj = 0; jj < 4; ++jj) acc[m][jj] = fmaf(pv[m], wv[jj], acc[m][jj]);
        }
        #pragma unroll
        for (int jj = 0; jj < 4; ++jj) {
            const int jcol = cg * 4 + jj;
            const float bj = b1[jcol];
            #pragma unroll
            for (int m = 0; m < 8; ++m) {
                const float hval = acc[m][jj] + bj;
                hT[jcol * HT_PITCH + rbase + m] = hval > 0.f ? hval : 0.f;
            }
        }
    }
    __syncthreads();
    {
        const int cg2 = tid & 15, rg2 = tid >> 4, rb2 = rg2 * 4;
        float acc2[4][9];
        #pragma unroll
        for (int m = 0; m < 4; ++m)
            #pragma unroll
            for (int jj = 0; jj < 9; ++jj) acc2[m][jj] = 0.f;
        const float* w2base = W2 + cg2 * 9;
        for (int h = 0; h < HIDN; ++h) {
            const float4 hv4 = *reinterpret_cast<const float4*>(hT + h * HT_PITCH + rb2);
            const float hv[4] = {hv4.x, hv4.y, hv4.z, hv4.w};
            float wv[9];
            #pragma unroll
            for (int jj = 0; jj < 9; ++jj) wv[jj] = w2base[h * PDIM + jj];
            #pragma unroll
            for (int m = 0; m < 4; ++m)
                #pragma unroll
                for (int jj = 0; jj < 9; ++jj) acc2[m][jj] = fmaf(hv[m], wv[jj], acc2[m][jj]);
        }
        float bv[9];
        #pragma unroll
        for (int jj = 0; jj < 9; ++jj) bv[jj] = b2[cg2 * 9 + jj];
        float* fb = folded + ((size_t)b * CC + cg2) * (HH * WW);
        #pragma unroll
        for (int m = 0; m < 4; ++m) {
            const int l = tile_base + rb2 + m, a = l >> 7, bb = l & 127;
            #pragma unroll
            for (int jj = 0; jj < 9; ++jj) {
                const int i = jj / 3, j2 = jj - i * 3;
                const int ypad = 2 * a + i, xpad = 2 * bb + j2;
                if (ypad >= 1 && xpad >= 1)
                    atomicAdd(fb + (ypad - 1) * WW + (xpad - 1), acc2[m][jj] + bv[jj]);
            }
        }
    }
}

__global__ __launch_bounds__(256) void norm_softmax_kernel_fb(
    float* __restrict__ out, const float* __restrict__ Wc, const float* __restrict__ bc)
{
    const int xo = threadIdx.x, yo = blockIdx.x & 255, b = blockIdx.x >> 8;
    const int yp = yo + 1, xp = xo + 1;
    const float cy = ((yp & 1) || yp == 256) ? 1.f : 2.f;
    const float cx = ((xp & 1) || xp == 256) ? 1.f : 2.f;
    const float inv = 1.f / (cy * cx + 1e-6f);
    const size_t base = ((size_t)b * CC) * (HH * WW) + (size_t)yo * WW + xo;
    float nrm[CC];
    #pragma unroll
    for (int c = 0; c < CC; ++c) nrm[c] = out[base + (size_t)c * (HH * WW)] * inv;
    float logits[CC];
    #pragma unroll
    for (int o = 0; o < CC; ++o) {
        float s = bc[o];
        #pragma unroll
        for (int c = 0; c < CC; ++c) s = fmaf(Wc[o * CC + c], nrm[c], s);
        logits[o] = s;
    }
    float mx = logits[0];
    #pragma unroll
    for (int o = 1; o < CC; ++o) mx = fmaxf(mx, logits[o]);
    float se = 0.f;
    #pragma unroll
    for (int o = 0; o < CC; ++o) { logits[o] = expf(logits[o] - mx); se += logits[o]; }
    const float isum = 1.f / se;
    #pragma unroll
    for (int c = 0; c < CC; ++c)
        out[base + (size_t)c * (HH * WW)] = nrm[c] * logits[c] * isum;
}

// ---------------------------------------------------------------------------
extern "C" void kernel_launch(void* const* d_in, const int* in_sizes, int n_in,
                              void* d_out, int out_size, void* d_ws, size_t ws_size,
                              hipStream_t stream)
{
    const float* x  = (const float*)d_in[0];
    const float* W1 = (const float*)d_in[1];
    const float* b1 = (const float*)d_in[2];
    const float* W2 = (const float*)d_in[3];
    const float* b2 = (const float*)d_in[4];
    const float* Wc = (const float*)d_in[5];
    const float* bc = (const float*)d_in[6];
    float* out = (float*)d_out;

    if (ws_size >= WS_NEEDED) {
        _Float16* og  = (_Float16*)d_ws;
        _Float16* W1T = (_Float16*)((char*)d_ws + W1T_OFF);
        _Float16* W2T = (_Float16*)((char*)d_ws + W2T_OFF);

        prep_kernel<<<dim3(80), dim3(256), 0, stream>>>(W1, W2, W1T, W2T);
        // 32 batches x 128 patch rows
        mlp_kernel<<<dim3(32 * 128), dim3(256), 0, stream>>>(x, W1T, b1, W2T, b2, og);
        // 32 batches x 256 output rows
        gather_kernel<<<dim3(32 * 256), dim3(256), 0, stream>>>(og, Wc, bc, out);
    } else {
        hipMemsetAsync(d_out, 0, (size_t)out_size * sizeof(float), stream);
        mlp_fold_kernel_fb<<<dim3(32 * 256), dim3(256), 0, stream>>>(x, W1, b1, W2, b2, out);
        norm_softmax_kernel_fb<<<dim3(32 * 256), dim3(256), 0, stream>>>(out, Wc, bc);
    }
}